// Round 3
// baseline (502.477 us; speedup 1.0000x reference)
//
#include <hip/hip_runtime.h>
#include <stdint.h>

#define B_ROWS 8192
#define DIM 4096
#define E_CODES 512
#define MARGIN 16.0f

typedef __attribute__((ext_vector_type(8))) short short8;
typedef __attribute__((ext_vector_type(4))) float floatx4;

// ---- workspace layout (float units) ----
#define WS_SCORES 0                       // 8192*512 floats (accumulated dot partials)
#define WS_ENORM  4194304                 // 512 floats
#define WS_COUNTS 4194816                 // 512 ints
#define WS_LOSS   4195328                 // 1 float
#define WS_XNORM  4195329                 // 1 float (sum of x^2, 4x overcounted)

// ---- output layout (float units) ----
#define O_LOSS 0
#define O_Q    1
#define O_PERP 33554433
#define O_ENC  33554434

// ---------------- codebook norms ----------------
__global__ __launch_bounds__(64) void k_enorm(const float* __restrict__ cb, float* __restrict__ enorm) {
    const int e = blockIdx.x;
    const int lane = threadIdx.x;
    const float4* c4 = (const float4*)(cb + (size_t)e * DIM);
    float p = 0.f;
#pragma unroll
    for (int j = 0; j < 16; j++) {
        float4 v = c4[j * 64 + lane];
        p = fmaf(v.x, v.x, fmaf(v.y, v.y, fmaf(v.z, v.z, fmaf(v.w, v.w, p))));
    }
    for (int off = 32; off; off >>= 1) p += __shfl_down(p, off);
    if (lane == 0) enorm[e] = p;
}

// pack two fp32 into (bf16(hi)<<16)|bf16(lo) by truncation — one v_perm_b32
__device__ inline uint32_t pk2(float hi, float lo) {
    return __builtin_amdgcn_perm(__float_as_uint(hi), __float_as_uint(lo), 0x07060302u);
}

// ---------------- partial-dot GEMM: scores[b][e] += <bf16(x),bf16(e)> over half of K ----------------
// BM=64, BN=128, BK=64, K-split=2. 512 threads = 8 waves (2m x 4n), wave = 32x32 via 2x2 frags.
// grid = 2 * 128 * 4 = 1024 blocks -> 4 blocks/CU, 32 waves/CU (100% nominal occupancy).
// Swizzle: same-bm quad {h, h+8, h+16, h+24} lands on one XCD (dispatch round-robin) -> X L2-shared.
// Also accumulates sum(x^2) over staged A tiles (4x overcounted across bn) for the loss.
#define LDK 72  // padded LDS row stride (bf16 elems)
__global__ __launch_bounds__(512) void k_gemm(const float* __restrict__ X, const float* __restrict__ CB,
                                              float* __restrict__ scores, float* __restrict__ xnorm_sum) {
    __shared__ __align__(16) unsigned short As[64 * LDK];
    __shared__ __align__(16) unsigned short Bs[128 * LDK];
    __shared__ float xred[8];
    const int id = blockIdx.x;
    const int ks = id >> 9;          // K half
    const int h = id & 511;
    const int bn = (h >> 3) & 3;
    const int bm = ((h >> 5) << 3) | (h & 7);
    const int tid = threadIdx.x;
    const int lane = tid & 63;
    const int w = tid >> 6, wr = w >> 2, wc = w & 3;
    const int m16 = lane & 15, q4 = lane >> 4;

    const int rA = tid >> 3, cA = (tid & 7) * 8;    // A: 64 x 64 floats, 8/thread
    const int rB = tid >> 2, cB = (tid & 3) * 16;   // B: 128 x 64 floats, 16/thread
    const float* xg = X + (size_t)(bm * 64 + rA) * DIM + cA + (ks << 11);
    const float* cg = CB + (size_t)(bn * 128 + rB) * DIM + cB + (ks << 11);

    floatx4 acc[2][2];
#pragma unroll
    for (int i = 0; i < 2; i++)
#pragma unroll
        for (int j = 0; j < 2; j++) acc[i][j] = (floatx4){0.f, 0.f, 0.f, 0.f};
    float xn = 0.f;

    for (int kt = 0; kt < 2048; kt += 64) {
        const float4* xa = (const float4*)(xg + kt);
        const float4* ca = (const float4*)(cg + kt);
        float4 xv0 = xa[0], xv1 = xa[1];
        float4 cv0 = ca[0], cv1 = ca[1], cv2 = ca[2], cv3 = ca[3];
        xn = fmaf(xv0.x, xv0.x, fmaf(xv0.y, xv0.y, fmaf(xv0.z, xv0.z, fmaf(xv0.w, xv0.w, xn))));
        xn = fmaf(xv1.x, xv1.x, fmaf(xv1.y, xv1.y, fmaf(xv1.z, xv1.z, fmaf(xv1.w, xv1.w, xn))));
        __syncthreads();  // previous tile's frag reads complete
        *(uint4*)(&As[rA * LDK + cA]) = make_uint4(pk2(xv0.y, xv0.x), pk2(xv0.w, xv0.z), pk2(xv1.y, xv1.x), pk2(xv1.w, xv1.z));
        *(uint4*)(&Bs[rB * LDK + cB])     = make_uint4(pk2(cv0.y, cv0.x), pk2(cv0.w, cv0.z), pk2(cv1.y, cv1.x), pk2(cv1.w, cv1.z));
        *(uint4*)(&Bs[rB * LDK + cB + 8]) = make_uint4(pk2(cv2.y, cv2.x), pk2(cv2.w, cv2.z), pk2(cv3.y, cv3.x), pk2(cv3.w, cv3.z));
        __syncthreads();
        short8 a[2][2], b[2][2];
#pragma unroll
        for (int i = 0; i < 2; i++)
#pragma unroll
            for (int kk = 0; kk < 2; kk++) {
                a[i][kk] = *(const short8*)(&As[(wr * 32 + i * 16 + m16) * LDK + kk * 32 + q4 * 8]);
                b[i][kk] = *(const short8*)(&Bs[(wc * 32 + i * 16 + m16) * LDK + kk * 32 + q4 * 8]);
            }
#pragma unroll
        for (int kk = 0; kk < 2; kk++)
#pragma unroll
            for (int i = 0; i < 2; i++)
#pragma unroll
                for (int j = 0; j < 2; j++)
                    acc[i][j] = __builtin_amdgcn_mfma_f32_16x16x32_bf16(a[i][kk], b[j][kk], acc[i][j], 0, 0, 0);
    }

    // epilogue: accumulate partial dots into scores (both K-halves add here)
#pragma unroll
    for (int j = 0; j < 2; j++) {
        const int col = bn * 128 + wc * 32 + j * 16 + m16;
#pragma unroll
        for (int i = 0; i < 2; i++) {
            const int row0 = bm * 64 + wr * 32 + i * 16 + q4 * 4;
#pragma unroll
            for (int rr = 0; rr < 4; rr++)
                atomicAdd(&scores[(size_t)(row0 + rr) * E_CODES + col], acc[i][j][rr]);
        }
    }

    // block-reduce sum(x^2)
    for (int off = 32; off; off >>= 1) xn += __shfl_down(xn, off);
    if (lane == 0) xred[w] = xn;
    __syncthreads();
    if (tid == 0) {
        float s = 0.f;
        for (int k = 0; k < 8; k++) s += xred[k];
        atomicAdd(xnorm_sum, s);
    }
}

// ---------------- fused: wave-per-row argmin (+rare exact refine), quantize, one-hot, loss ----------------
// grid = 2048 x 256; one row per wave; no LDS/syncthreads. X is read ONLY for multi-candidate rows.
__global__ __launch_bounds__(256) void k_fused(const float* __restrict__ X, const float* __restrict__ CB,
                                               const float* __restrict__ scores, const float* __restrict__ enorm,
                                               int* __restrict__ counts, float* __restrict__ loss_sum,
                                               float* __restrict__ out) {
    const int tid = threadIdx.x;
    const int lane = tid & 63, w = tid >> 6;
    const int row = blockIdx.x * 4 + w;

    const float* sr = scores + (size_t)row * E_CODES;
    float s[8];
#pragma unroll
    for (int g = 0; g < 8; g++) s[g] = enorm[g * 64 + lane] - 2.0f * sr[g * 64 + lane];

    // wave argmin (approx scores), tie -> lower index
    float mv = s[0]; int mi = lane;
#pragma unroll
    for (int g = 1; g < 8; g++) { if (s[g] < mv) { mv = s[g]; mi = g * 64 + lane; } }
    for (int off = 32; off; off >>= 1) {
        float ov = __shfl_xor(mv, off); int oi = __shfl_xor(mi, off);
        if (ov < mv || (ov == mv && oi < mi)) { mv = ov; mi = oi; }
    }
    const float thr = mv + MARGIN;

    unsigned long long bal[8]; int nc = 0;
#pragma unroll
    for (int g = 0; g < 8; g++) { bal[g] = __ballot(s[g] <= thr); nc += __popcll(bal[g]); }

    int beste = mi;
    if (nc > 1) {
        // exact fp32 refinement (identical arithmetic to the absmax=0 R2 kernel)
        const float4* xr4 = (const float4*)(X + (size_t)row * DIM);
        float bestd = 3.0e38f; beste = 1 << 30;
#pragma unroll 1
        for (int g = 0; g < 8; g++) {
            unsigned long long mask = bal[g];
            while (mask) {
                const int b = __builtin_ctzll(mask); mask &= mask - 1;
                const int e = g * 64 + b;
                const float4* cr4 = (const float4*)(CB + (size_t)e * DIM);
                float p = 0.f;
#pragma unroll
                for (int i = 0; i < 16; i++) {
                    float4 x = xr4[i * 64 + lane];
                    float4 c = cr4[i * 64 + lane];
                    float dx = x.x - c.x, dy = x.y - c.y, dz = x.z - c.z, dw = x.w - c.w;
                    p = fmaf(dx, dx, fmaf(dy, dy, fmaf(dz, dz, fmaf(dw, dw, p))));
                }
                for (int off = 32; off; off >>= 1) p += __shfl_xor(p, off);
                if (p < bestd || (p == bestd && e < beste)) { bestd = p; beste = e; }
            }
        }
    }

    // quantized_st: write q directly (|fl(x+fl(q-x)) - q| <= ~4e-7 << threshold).
    // per-dword lane-contiguous stores: coalesced despite the +1 global misalignment.
    const float* cq = CB + (size_t)beste * DIM;
    float* oq = out + O_Q + (size_t)row * DIM;
#pragma unroll
    for (int i = 0; i < 64; i++) oq[i * 64 + lane] = cq[i * 64 + lane];

    // one-hot row (O_ENC is 8B-aligned -> float2)
    float2* oe2 = (float2*)(out + O_ENC + (size_t)row * E_CODES);
#pragma unroll
    for (int k = 0; k < 4; k++) {
        const int e0 = (k * 64 + lane) * 2;
        float2 v; v.x = (e0 == beste) ? 1.0f : 0.0f; v.y = (e0 + 1 == beste) ? 1.0f : 0.0f;
        oe2[k * 64 + lane] = v;
    }

    if (lane == 0) {
        atomicAdd(&counts[beste], 1);
        // loss partial: dist_row = ||x_row||^2 + (enorm[e*] - 2<x,e*>); the ||x||^2 part is summed in k_gemm
        const float ssel = enorm[beste] - 2.0f * sr[beste];
        atomicAdd(loss_sum, ssel);
    }
}

// ---------------- loss + perplexity ----------------
__global__ __launch_bounds__(512) void k_final(const int* __restrict__ counts, const float* __restrict__ loss_sum,
                                               const float* __restrict__ xnorm_sum, float* __restrict__ out) {
    const int tid = threadIdx.x;
    const int lane = tid & 63, w = tid >> 6;
    __shared__ float r[8];
    const float p = (float)counts[tid] * (1.0f / 8192.0f);
    float h = p * logf(p + 1e-10f);
    for (int off = 32; off; off >>= 1) h += __shfl_down(h, off);
    if (lane == 0) r[w] = h;
    __syncthreads();
    if (tid == 0) {
        float H = 0.f;
        for (int k = 0; k < 8; k++) H += r[k];
        out[O_PERP] = expf(-H);
        // xnorm_sum is 4x overcounted (staged once per bn tile)
        const float dist_total = loss_sum[0] + 0.25f * xnorm_sum[0];
        out[O_LOSS] = dist_total * (1.25f / 33554432.0f);  // q_latent + 0.25*e_latent = 1.25*MSE
    }
}

extern "C" void kernel_launch(void* const* d_in, const int* in_sizes, int n_in,
                              void* d_out, int out_size, void* d_ws, size_t ws_size,
                              hipStream_t stream) {
    const float* X  = (const float*)d_in[0];   // inputs  [8192, 8,8,8,8] -> [8192,4096]
    const float* CB = (const float*)d_in[1];   // codebook [512, 4096]
    float* out = (float*)d_out;
    float* ws  = (float*)d_ws;
    float* scores = ws + WS_SCORES;
    float* enorm  = ws + WS_ENORM;
    int*   counts = (int*)(ws + WS_COUNTS);
    float* loss_s = ws + WS_LOSS;
    float* xnorm  = ws + WS_XNORM;

    // scores must start at 0 (atomic accumulation); counts+loss+xnorm contiguous
    hipMemsetAsync(scores, 0, (size_t)B_ROWS * E_CODES * sizeof(float), stream);
    hipMemsetAsync(counts, 0, (E_CODES + 2) * sizeof(int), stream);

    k_enorm<<<E_CODES, 64, 0, stream>>>(CB, enorm);
    k_gemm<<<1024, 512, 0, stream>>>(X, CB, scores, xnorm);
    k_fused<<<B_ROWS / 4, 256, 0, stream>>>(X, CB, scores, enorm, counts, loss_s, out);
    k_final<<<1, 512, 0, stream>>>(counts, loss_s, xnorm, out);
}

// Round 4
// 468.397 us; speedup vs baseline: 1.0728x; 1.0728x over previous
//
#include <hip/hip_runtime.h>
#include <stdint.h>

#define B_ROWS 8192
#define DIM 4096
#define E_CODES 512
#define MARGIN 16.0f

typedef __attribute__((ext_vector_type(8))) short short8;
typedef __attribute__((ext_vector_type(4))) float floatx4;

// ---- workspace layout (float units) ---- (16.8 MB total, same footprint as R1-R3)
#define WS_SCORES 0                       // 8192*512 floats (final scores, direct-stored)
#define WS_ENORM  4194304                 // 512 floats
#define WS_COUNTS 4194816                 // 512 ints
#define WS_LOSS   4195328                 // 1 float
#define WS_XNORM  4195329                 // 1 float (exact sum of x^2)

// ---- output layout (float units) ----
#define O_LOSS 0
#define O_Q    1
#define O_PERP 33554433
#define O_ENC  33554434
// bf16 staging inside out's Q region (overwritten by k_fused afterwards):
// Xb at float idx 4 (byte 16, 16B-aligned), 33.5M shorts = 16,777,216 floats
#define XB_F_OFF  4
#define CBB_F_OFF (4 + 16777216)          // CBb: 2.1M shorts = 1,048,576 floats; ends < O_PERP

// pack two fp32 into (bf16(hi)<<16)|bf16(lo) by truncation — one v_perm_b32
__device__ inline uint32_t pk2(float hi, float lo) {
    return __builtin_amdgcn_perm(__float_as_uint(hi), __float_as_uint(lo), 0x07060302u);
}

#define GLD_LDS16(g, l) \
    __builtin_amdgcn_global_load_lds((const __attribute__((address_space(1))) void*)(g), \
                                     (__attribute__((address_space(3))) void*)(l), 16, 0, 0)

// ---------------- X fp32 -> bf16 (trunc) + exact sum(x^2) ----------------
// 2048 blocks x 256 thr; fully coalesced (16B read / 8B write per lane).
__global__ __launch_bounds__(256) void k_convert(const float* __restrict__ X,
                                                 unsigned short* __restrict__ Xb,
                                                 float* __restrict__ xnorm_sum) {
    const int tid = threadIdx.x;
    const int lane = tid & 63, w = tid >> 6;
    const float4* x4 = (const float4*)X + (size_t)blockIdx.x * 4096;
    uint2* o2 = (uint2*)Xb + (size_t)blockIdx.x * 4096;
    float xn = 0.f;
#pragma unroll
    for (int i = 0; i < 16; i++) {
        float4 v = x4[i * 256 + tid];
        xn = fmaf(v.x, v.x, fmaf(v.y, v.y, fmaf(v.z, v.z, fmaf(v.w, v.w, xn))));
        o2[i * 256 + tid] = make_uint2(pk2(v.y, v.x), pk2(v.w, v.z));
    }
    __shared__ float r[4];
    for (int off = 32; off; off >>= 1) xn += __shfl_down(xn, off);
    if (lane == 0) r[w] = xn;
    __syncthreads();
    if (tid == 0) atomicAdd(xnorm_sum, ((r[0] + r[1]) + r[2]) + r[3]);
}

// ---------------- CB fp32 -> bf16 (trunc) + enorm ----------------
__global__ __launch_bounds__(64) void k_cvt_cb(const float* __restrict__ CB,
                                               unsigned short* __restrict__ CBb,
                                               float* __restrict__ enorm) {
    const int e = blockIdx.x;
    const int lane = threadIdx.x;
    const float4* c4 = (const float4*)CB + (size_t)e * 1024;
    uint2* o2 = (uint2*)CBb + (size_t)e * 1024;
    float p = 0.f;
#pragma unroll
    for (int i = 0; i < 16; i++) {
        float4 v = c4[i * 64 + lane];
        p = fmaf(v.x, v.x, fmaf(v.y, v.y, fmaf(v.z, v.z, fmaf(v.w, v.w, p))));
        o2[i * 64 + lane] = make_uint2(pk2(v.y, v.x), pk2(v.w, v.z));
    }
    for (int off = 32; off; off >>= 1) p += __shfl_down(p, off);
    if (lane == 0) enorm[e] = p;
}

// ---------------- bf16 score GEMM: scores[b][e] = ||e||^2 - 2*<xb,eb> ----------------
// BM=128, BN=64, BK=32, 256 thr = 4 waves (2m x 2n), wave = 64x32 via 4x2 frags of 16x16x32.
// grid = 64*8 = 512 blocks (2/CU). Staging via global_load_lds width=16 (async DMA, no VGPR trip).
// LDS rows = 32 bf16 = 64 B, unpadded (required by DMA lane ordering; conflict-free for this frag read).
// Swizzle: same-bm octet {h, h+8,..., h+56} lands on one XCD -> X tile L2-shared across bn.
__global__ __launch_bounds__(256) void k_gemm2(const unsigned short* __restrict__ Xb,
                                               const unsigned short* __restrict__ CBb,
                                               const float* __restrict__ enorm,
                                               float* __restrict__ scores) {
    __shared__ __align__(16) unsigned short As[128 * 32];  // 8 KB
    __shared__ __align__(16) unsigned short Bs[64 * 32];   // 4 KB
    const int h = blockIdx.x;
    const int bn = (h >> 3) & 7;
    const int bm = ((h >> 6) << 3) | (h & 7);
    const int tid = threadIdx.x;
    const int lane = tid & 63;
    const int w = tid >> 6, wr = w >> 1, wc = w & 1;
    const int m16 = lane & 15, q4 = lane >> 4;

    // DMA staging: wave w loads A rows [32w,32w+32) (2 instrs) and B rows [16w,16w+16) (1 instr).
    // lane L -> row (L>>2), k-chunk (L&3)*8 elems; LDS side = uniform base + lane*16 (HW).
    const int lr = lane >> 2, lc = (lane & 3) * 8;
    const unsigned short* xg0 = Xb + (size_t)(bm * 128 + w * 32 + lr) * DIM + lc;
    const unsigned short* xg1 = xg0 + 16 * DIM;
    const unsigned short* bg  = CBb + (size_t)(bn * 64 + w * 16 + lr) * DIM + lc;
    unsigned short* lA0 = &As[(2 * w) * 512];
    unsigned short* lA1 = &As[(2 * w + 1) * 512];
    unsigned short* lB  = &Bs[w * 512];

    floatx4 acc[4][2];
#pragma unroll
    for (int f = 0; f < 4; f++)
#pragma unroll
        for (int j = 0; j < 2; j++) acc[f][j] = (floatx4){0.f, 0.f, 0.f, 0.f};

    for (int kt = 0; kt < DIM; kt += 32) {
        GLD_LDS16(xg0 + kt, lA0);
        GLD_LDS16(xg1 + kt, lA1);
        GLD_LDS16(bg + kt, lB);
        __syncthreads();  // drains DMA (vmcnt) + joins waves
        short8 a[4], b[2];
#pragma unroll
        for (int f = 0; f < 4; f++) a[f] = *(const short8*)(&As[(wr * 64 + f * 16 + m16) * 32 + q4 * 8]);
#pragma unroll
        for (int j = 0; j < 2; j++) b[j] = *(const short8*)(&Bs[(wc * 32 + j * 16 + m16) * 32 + q4 * 8]);
#pragma unroll
        for (int f = 0; f < 4; f++)
#pragma unroll
            for (int j = 0; j < 2; j++)
                acc[f][j] = __builtin_amdgcn_mfma_f32_16x16x32_bf16(a[f], b[j], acc[f][j], 0, 0, 0);
        __syncthreads();  // frag reads complete before next tile's DMA overwrites
    }

    // epilogue: C/D layout col=lane&15 (code idx), row=(lane>>4)*4+reg (x row) — validated R1-R3
#pragma unroll
    for (int j = 0; j < 2; j++) {
        const int col = bn * 64 + wc * 32 + j * 16 + m16;
        const float en = enorm[col];
#pragma unroll
        for (int f = 0; f < 4; f++) {
            const int row0 = bm * 128 + wr * 64 + f * 16 + q4 * 4;
#pragma unroll
            for (int rr = 0; rr < 4; rr++)
                scores[(size_t)(row0 + rr) * E_CODES + col] = en - 2.0f * acc[f][j][rr];
        }
    }
}

// ---------------- fused: wave-per-row argmin (+rare exact refine), quantize, one-hot, loss ----------------
__global__ __launch_bounds__(256) void k_fused(const float* __restrict__ X, const float* __restrict__ CB,
                                               const float* __restrict__ scores,
                                               int* __restrict__ counts, float* __restrict__ loss_sum,
                                               float* __restrict__ out) {
    const int tid = threadIdx.x;
    const int lane = tid & 63, w = tid >> 6;
    const int row = blockIdx.x * 4 + w;

    const float* sr = scores + (size_t)row * E_CODES;
    float s[8];
#pragma unroll
    for (int g = 0; g < 8; g++) s[g] = sr[g * 64 + lane];

    // wave argmin (approx scores), tie -> lower index
    float mv = s[0]; int mi = lane;
#pragma unroll
    for (int g = 1; g < 8; g++) { if (s[g] < mv) { mv = s[g]; mi = g * 64 + lane; } }
    for (int off = 32; off; off >>= 1) {
        float ov = __shfl_xor(mv, off); int oi = __shfl_xor(mi, off);
        if (ov < mv || (ov == mv && oi < mi)) { mv = ov; mi = oi; }
    }
    const float thr = mv + MARGIN;

    unsigned long long bal[8]; int nc = 0;
#pragma unroll
    for (int g = 0; g < 8; g++) { bal[g] = __ballot(s[g] <= thr); nc += __popcll(bal[g]); }

    int beste = mi;
    if (nc > 1) {
        // exact fp32 refinement (identical arithmetic to validated rounds)
        const float4* xr4 = (const float4*)(X + (size_t)row * DIM);
        float bestd = 3.0e38f; beste = 1 << 30;
#pragma unroll 1
        for (int g = 0; g < 8; g++) {
            unsigned long long mask = bal[g];
            while (mask) {
                const int b = __builtin_ctzll(mask); mask &= mask - 1;
                const int e = g * 64 + b;
                const float4* cr4 = (const float4*)(CB + (size_t)e * DIM);
                float p = 0.f;
#pragma unroll
                for (int i = 0; i < 16; i++) {
                    float4 x = xr4[i * 64 + lane];
                    float4 c = cr4[i * 64 + lane];
                    float dx = x.x - c.x, dy = x.y - c.y, dz = x.z - c.z, dw = x.w - c.w;
                    p = fmaf(dx, dx, fmaf(dy, dy, fmaf(dz, dz, fmaf(dw, dw, p))));
                }
                for (int off = 32; off; off >>= 1) p += __shfl_xor(p, off);
                if (p < bestd || (p == bestd && e < beste)) { bestd = p; beste = e; }
            }
        }
    }

    // quantized_st: write q directly (|fl(x+fl(q-x)) - q| tiny vs threshold); coalesced dword stores
    const float* cq = CB + (size_t)beste * DIM;
    float* oq = out + O_Q + (size_t)row * DIM;
#pragma unroll
    for (int i = 0; i < 64; i++) oq[i * 64 + lane] = cq[i * 64 + lane];

    // one-hot row (O_ENC is 8B-aligned -> float2)
    float2* oe2 = (float2*)(out + O_ENC + (size_t)row * E_CODES);
#pragma unroll
    for (int k = 0; k < 4; k++) {
        const int e0 = (k * 64 + lane) * 2;
        float2 v; v.x = (e0 == beste) ? 1.0f : 0.0f; v.y = (e0 + 1 == beste) ? 1.0f : 0.0f;
        oe2[k * 64 + lane] = v;
    }

    if (lane == 0) {
        atomicAdd(&counts[beste], 1);
        // dist_row = ||x||^2 + score[beste]; the ||x||^2 part is summed exactly in k_convert
        atomicAdd(loss_sum, sr[beste]);
    }
}

// ---------------- loss + perplexity ----------------
__global__ __launch_bounds__(512) void k_final(const int* __restrict__ counts, const float* __restrict__ loss_sum,
                                               const float* __restrict__ xnorm_sum, float* __restrict__ out) {
    const int tid = threadIdx.x;
    const int lane = tid & 63, w = tid >> 6;
    __shared__ float r[8];
    const float p = (float)counts[tid] * (1.0f / 8192.0f);
    float h = p * logf(p + 1e-10f);
    for (int off = 32; off; off >>= 1) h += __shfl_down(h, off);
    if (lane == 0) r[w] = h;
    __syncthreads();
    if (tid == 0) {
        float H = 0.f;
        for (int k = 0; k < 8; k++) H += r[k];
        out[O_PERP] = expf(-H);
        const float dist_total = loss_sum[0] + xnorm_sum[0];
        out[O_LOSS] = dist_total * (1.25f / 33554432.0f);  // q_latent + 0.25*e_latent = 1.25*MSE
    }
}

extern "C" void kernel_launch(void* const* d_in, const int* in_sizes, int n_in,
                              void* d_out, int out_size, void* d_ws, size_t ws_size,
                              hipStream_t stream) {
    const float* X  = (const float*)d_in[0];   // inputs  [8192, 8,8,8,8] -> [8192,4096]
    const float* CB = (const float*)d_in[1];   // codebook [512, 4096]
    float* out = (float*)d_out;
    float* ws  = (float*)d_ws;
    float* scores = ws + WS_SCORES;
    float* enorm  = ws + WS_ENORM;
    int*   counts = (int*)(ws + WS_COUNTS);
    float* loss_s = ws + WS_LOSS;
    float* xnorm  = ws + WS_XNORM;
    // bf16 staging lives in out's Q region; fully overwritten by k_fused afterwards
    unsigned short* Xb  = (unsigned short*)(out + XB_F_OFF);
    unsigned short* CBb = (unsigned short*)(out + CBB_F_OFF);

    hipMemsetAsync(counts, 0, (E_CODES + 2) * sizeof(int), stream);

    k_convert<<<2048, 256, 0, stream>>>(X, Xb, xnorm);
    k_cvt_cb<<<E_CODES, 64, 0, stream>>>(CB, CBb, enorm);
    k_gemm2<<<512, 256, 0, stream>>>(Xb, CBb, enorm, scores);
    k_fused<<<B_ROWS / 4, 256, 0, stream>>>(X, CB, scores, counts, loss_s, out);
    k_final<<<1, 512, 0, stream>>>(counts, loss_s, xnorm, out);
}